// Round 1
// baseline (74.418 us; speedup 1.0000x reference)
//
#include <hip/hip_runtime.h>
#include <hip/hip_bf16.h>

// Problem constants
constexpr int BB = 64;    // batch
constexpr int SS = 512;   // seq len
constexpr int HH = 768;   // hidden
constexpr int LL = 9;     // labels
constexpr int NCHUNK = 16;
constexpr int CHUNK = 32; // SS / NCHUNK

// ---------------------------------------------------------------------------
// Kernel A: emissions[pos, l] = dot(hidden[pos,:], W[:,l]) + b[l]
// One wave per position. Lane holds k-slice of 12 (768 = 64*12); its W slice
// (12 rows x 9 = 108 floats) lives in registers. Butterfly reduce 9 accs.
// ---------------------------------------------------------------------------
__global__ __launch_bounds__(256) void emis_kernel(
    const float* __restrict__ hs, const float* __restrict__ W,
    const float* __restrict__ bias, float* __restrict__ em) {
  const int lane = threadIdx.x & 63;
  const int wid  = (int)((blockIdx.x * blockDim.x + threadIdx.x) >> 6);
  const int nw   = (int)((gridDim.x * blockDim.x) >> 6);

  const int k0 = lane * 12;

  // Per-lane W slice in registers: rows k0..k0+11 (contiguous 108 floats).
  float w[108];
#pragma unroll
  for (int q = 0; q < 27; ++q) {
    float4 t = *reinterpret_cast<const float4*>(W + (size_t)k0 * LL + q * 4);
    w[q * 4 + 0] = t.x; w[q * 4 + 1] = t.y;
    w[q * 4 + 2] = t.z; w[q * 4 + 3] = t.w;
  }
  float bv[LL];
#pragma unroll
  for (int l = 0; l < LL; ++l) bv[l] = bias[l];

  for (int pos = wid; pos < BB * SS; pos += nw) {
    const float* h = hs + (size_t)pos * HH + k0;
    float4 h0 = *reinterpret_cast<const float4*>(h + 0);
    float4 h1 = *reinterpret_cast<const float4*>(h + 4);
    float4 h2 = *reinterpret_cast<const float4*>(h + 8);
    float hv[12] = {h0.x, h0.y, h0.z, h0.w,
                    h1.x, h1.y, h1.z, h1.w,
                    h2.x, h2.y, h2.z, h2.w};
    float acc[LL];
#pragma unroll
    for (int l = 0; l < LL; ++l) acc[l] = 0.f;
#pragma unroll
    for (int mm = 0; mm < 12; ++mm) {
      float hh = hv[mm];
#pragma unroll
      for (int l = 0; l < LL; ++l) acc[l] += hh * w[mm * LL + l];
    }
    // 64-lane butterfly reduction of the 9 partials
#pragma unroll
    for (int off = 32; off; off >>= 1) {
#pragma unroll
      for (int l = 0; l < LL; ++l) acc[l] += __shfl_xor(acc[l], off);
    }
    if (lane == 0) {
      float* o = em + (size_t)pos * LL;
#pragma unroll
      for (int l = 0; l < LL; ++l) o[l] = acc[l] + bv[l];
    }
  }
}

// ---------------------------------------------------------------------------
// Kernel B: per (batch, chunk) compute the 9x9 log-semiring product
//   M = prod_{t in chunk} A_t,  A_t[i,j] = trans[i,j] + em[t,j] (mask=1)
//                               A_t      = identity (diag 0, off -inf) (mask=0)
// Thread t<81 owns M[i][j]. Per step: M[i][j] = lse_k(M[i][k]+trans[k][j]) + em[j].
// ---------------------------------------------------------------------------
__global__ __launch_bounds__(128) void chunk_kernel(
    const float* __restrict__ em, const int* __restrict__ mask,
    const float* __restrict__ trans, float* __restrict__ chunkM) {
  const int b = blockIdx.x >> 4;
  const int c = blockIdx.x & 15;
  const int t = threadIdx.x;
  const bool act = t < 81;
  const int i = t / 9, j = t % 9;

  __shared__ float Ml[81];
  __shared__ float ems[LL];
  __shared__ int mks;

  float tc[9];
  if (act) {
#pragma unroll
    for (int k = 0; k < 9; ++k) tc[k] = trans[k * LL + j];
  }
  float mij = (i == j) ? 0.f : -1e30f;

  const int t0 = (c == 0) ? 1 : c * CHUNK;
  const int t1 = c * CHUNK + CHUNK;
  for (int tt = t0; tt < t1; ++tt) {
    if (act) Ml[t] = mij;
    if (t < LL) ems[t] = em[((size_t)(b * SS + tt)) * LL + t];
    if (t == 0) mks = mask[b * SS + tt];
    __syncthreads();
    if (act && mks) {
      float x[9];
      float m = -3e38f;
#pragma unroll
      for (int k = 0; k < 9; ++k) {
        x[k] = Ml[i * 9 + k] + tc[k];
        m = fmaxf(m, x[k]);
      }
      float s = 0.f;
#pragma unroll
      for (int k = 0; k < 9; ++k) s += __expf(x[k] - m);
      mij = m + __logf(s) + ems[j];
    }
    __syncthreads();
  }
  if (act) chunkM[(size_t)blockIdx.x * 81 + t] = mij;
}

// ---------------------------------------------------------------------------
// Kernel C: per batch: fold alpha0 through 16 chunk matrices, logsumexp with
// end_trans -> denom; compute numerator; write partial[b] = denom - num.
// One wave per batch.
// ---------------------------------------------------------------------------
__global__ __launch_bounds__(64) void final_kernel(
    const float* __restrict__ em, const int* __restrict__ mask,
    const int* __restrict__ labels, const float* __restrict__ st,
    const float* __restrict__ et, const float* __restrict__ trans,
    const float* __restrict__ chunkM, float* __restrict__ partials) {
  const int b = blockIdx.x;
  const int lane = threadIdx.x;

  float v = 0.f;
  if (lane < LL) v = st[lane] + em[((size_t)b * SS) * LL + lane];

  for (int c = 0; c < NCHUNK; ++c) {
    const float* M = chunkM + ((size_t)(b * NCHUNK + c)) * 81;
    float vk[9];
#pragma unroll
    for (int k = 0; k < 9; ++k) vk[k] = __shfl(v, k);
    if (lane < LL) {
      float x[9];
      float m = -3e38f;
#pragma unroll
      for (int k = 0; k < 9; ++k) {
        x[k] = vk[k] + M[k * 9 + lane];
        m = fmaxf(m, x[k]);
      }
      float s = 0.f;
#pragma unroll
      for (int k = 0; k < 9; ++k) s += __expf(x[k] - m);
      v = m + __logf(s);
    }
  }

  // denom = logsumexp_j(v[j] + end_trans[j])  (computed redundantly by all lanes)
  float vj[9];
#pragma unroll
  for (int k = 0; k < 9; ++k) vj[k] = __shfl(v, k) + et[k];
  float m = -3e38f;
#pragma unroll
  for (int k = 0; k < 9; ++k) m = fmaxf(m, vj[k]);
  float s = 0.f;
#pragma unroll
  for (int k = 0; k < 9; ++k) s += __expf(vj[k] - m);
  float denom = m + __logf(s);

  // numerator
  const int* lab = labels + b * SS;
  const int* mk  = mask + b * SS;
  float part = 0.f;
  int cnt = 0;
  for (int tt = lane; tt < SS; tt += 64) {
    int mv = mk[tt];
    cnt += mv;
    if (tt >= 1 && mv) {
      int lp = lab[tt - 1], lc = lab[tt];
      part += trans[lp * LL + lc] + em[((size_t)(b * SS + tt)) * LL + lc];
    }
  }
#pragma unroll
  for (int off = 32; off; off >>= 1) {
    part += __shfl_xor(part, off);
    cnt  += __shfl_xor(cnt, off);
  }
  if (lane == 0) {
    int last = cnt - 1;
    float num = st[lab[0]] + em[((size_t)b * SS) * LL + lab[0]] + part + et[lab[last]];
    partials[b] = denom - num;
  }
}

// ---------------------------------------------------------------------------
// Kernel D: sum 64 per-batch partials into the scalar output.
// ---------------------------------------------------------------------------
__global__ __launch_bounds__(64) void sum_kernel(
    const float* __restrict__ partials, float* __restrict__ out) {
  float p = partials[threadIdx.x];
#pragma unroll
  for (int off = 32; off; off >>= 1) p += __shfl_xor(p, off);
  if (threadIdx.x == 0) out[0] = p;
}

extern "C" void kernel_launch(void* const* d_in, const int* in_sizes, int n_in,
                              void* d_out, int out_size, void* d_ws, size_t ws_size,
                              hipStream_t stream) {
  const float* hs     = (const float*)d_in[0];
  const int*   mask   = (const int*)d_in[1];
  const int*   labels = (const int*)d_in[2];
  const float* W      = (const float*)d_in[3];
  const float* bias   = (const float*)d_in[4];
  const float* st     = (const float*)d_in[5];
  const float* et     = (const float*)d_in[6];
  const float* trans  = (const float*)d_in[7];

  float* em       = (float*)d_ws;                         // 64*512*9 floats
  float* chunkM   = em + (size_t)BB * SS * LL;            // 64*16*81 floats
  float* partials = chunkM + (size_t)BB * NCHUNK * 81;    // 64 floats

  emis_kernel<<<1024, 256, 0, stream>>>(hs, W, bias, em);
  chunk_kernel<<<BB * NCHUNK, 128, 0, stream>>>(em, mask, trans, chunkM);
  final_kernel<<<BB, 64, 0, stream>>>(em, mask, labels, st, et, trans, chunkM, partials);
  sum_kernel<<<1, 64, 0, stream>>>(partials, (float*)d_out);
}

// Round 2
// 54.677 us; speedup vs baseline: 1.3610x; 1.3610x over previous
//
#include <hip/hip_runtime.h>

typedef __attribute__((ext_vector_type(8))) short short8v;
typedef __attribute__((ext_vector_type(4))) float float4v;

constexpr int BB = 64, SS = 512, HH = 768, LL = 9, NCHUNK = 16, CHUNK = 32;
constexpr int WTS = 776;          // W^T LDS row stride in halfwords (bank-spread pad)
constexpr int NTILE = BB * SS / 16;  // 2048 MFMA tiles of 16 positions

// ---------------------------------------------------------------------------
// Kernel 1: emissions via MFMA bf16. One wave per 16-position tile.
// A = hs tile (16x32 per step, f32->bf16 via v_perm truncation),
// B = W^T staged in LDS as bf16 (cols 9..15 zero). C += A*B over 24 k-steps.
// Also zeroes out[0] (accumulated by kernel 3 via atomicAdd).
// ---------------------------------------------------------------------------
__global__ __launch_bounds__(256) void emis_mfma(
    const float* __restrict__ hs, const float* __restrict__ W,
    const float* __restrict__ bias, float* __restrict__ em,
    float* __restrict__ out) {
  if (blockIdx.x == 0 && threadIdx.x == 0) out[0] = 0.f;

  __shared__ __align__(16) unsigned short WT[16 * WTS];
  const int tid = threadIdx.x;
  // Stage W^T (bf16, truncated) into LDS: WT[col][k]
#pragma unroll
  for (int col = 0; col < 16; ++col) {
    for (int k = tid; k < HH; k += 256) {
      float v = (col < LL) ? W[(size_t)k * LL + col] : 0.f;
      WT[col * WTS + k] = (unsigned short)(__float_as_uint(v) >> 16);
    }
  }
  __syncthreads();

  const int lane = tid & 63;
  const int gw = blockIdx.x * 4 + (tid >> 6);  // tile id, 0..2047
  const int rc = lane & 15;                    // A row / B col / C col
  const int kb = lane >> 4;                    // k sub-block 0..3
  const int posb = gw * 16;

  const float* aptr = hs + (size_t)(posb + rc) * HH + kb * 8;
  const unsigned short* bptr = WT + rc * WTS + kb * 8;

  float4v acc = {0.f, 0.f, 0.f, 0.f};
#pragma unroll 4
  for (int s = 0; s < 24; ++s) {
    float4 a0 = *reinterpret_cast<const float4*>(aptr + s * 32);
    float4 a1 = *reinterpret_cast<const float4*>(aptr + s * 32 + 4);
    union { unsigned u[4]; short8v v; } A;
    A.u[0] = __builtin_amdgcn_perm(__float_as_uint(a0.y), __float_as_uint(a0.x), 0x07060302u);
    A.u[1] = __builtin_amdgcn_perm(__float_as_uint(a0.w), __float_as_uint(a0.z), 0x07060302u);
    A.u[2] = __builtin_amdgcn_perm(__float_as_uint(a1.y), __float_as_uint(a1.x), 0x07060302u);
    A.u[3] = __builtin_amdgcn_perm(__float_as_uint(a1.w), __float_as_uint(a1.z), 0x07060302u);
    short8v bv = *reinterpret_cast<const short8v*>(bptr + s * 32);
    acc = __builtin_amdgcn_mfma_f32_16x16x32_bf16(A.v, bv, acc, 0, 0, 0);
  }

  // C layout: col = lane&15, row = (lane>>4)*4 + r
  if (rc < LL) {
    float bval = bias[rc];
    int r0 = posb + kb * 4;
#pragma unroll
    for (int r = 0; r < 4; ++r)
      em[(size_t)(r0 + r) * LL + rc] = acc[r] + bval;
  }
}

// ---------------------------------------------------------------------------
// Kernel 2: per (batch, chunk) 9x9 log-semiring product, barrier-free.
// Row i of M evolves independently: M'[i][j] = lse_k(M[i][k]+trans[k][j]) + em[t][j].
// Lane slot = gw*63 + lane (lane<63); rows of 9 lanes never cross a wave
// (63 and 1296 are multiples of 9). Row broadcast via ds_bpermute.
// ---------------------------------------------------------------------------
constexpr int TOTSLOT = BB * NCHUNK * 81;  // 82944
constexpr int K2_WAVES = (TOTSLOT + 62) / 63;  // 1317
constexpr int K2_BLOCKS = (K2_WAVES + 3) / 4;  // 330

__global__ __launch_bounds__(256) void chunk_kernel(
    const float* __restrict__ em, const int* __restrict__ mask,
    const float* __restrict__ trans, float* __restrict__ chunkM) {
  const int lane = threadIdx.x & 63;
  const int gw = (int)((blockIdx.x * blockDim.x + threadIdx.x) >> 6);
  const int slot = gw * 63 + lane;
  const bool valid = (lane < 63) && (slot < TOTSLOT);

  int b = 0, c = 0, i = 0, j = 0, rowbase = 54;
  if (valid) {
    b = slot / 1296;
    int within = slot - b * 1296;
    c = within / 81;
    int r81 = within - c * 81;
    i = r81 / 9;
    j = r81 - i * 9;
    rowbase = lane - j;
  }

  int addr[9];
#pragma unroll
  for (int k = 0; k < 9; ++k) addr[k] = (rowbase + k) * 4;

  float tc[9];
#pragma unroll
  for (int k = 0; k < 9; ++k) tc[k] = trans[k * LL + j];

  float mij = (i == j) ? 0.f : -1e30f;

  const int t0 = c * CHUNK;
  const float* emp = em + ((size_t)(b * SS + t0)) * LL + j;
  const int* mkp = mask + b * SS + t0;
  float ev[CHUNK];
  int mv[CHUNK];
#pragma unroll
  for (int s = 0; s < CHUNK; ++s) { ev[s] = emp[(size_t)s * LL]; mv[s] = mkp[s]; }

#pragma unroll
  for (int s = 0; s < CHUNK; ++s) {
    float x[9];
    float m = -3e38f;
#pragma unroll
    for (int k = 0; k < 9; ++k) {
      x[k] = __int_as_float(
                 __builtin_amdgcn_ds_bpermute(addr[k], __float_as_int(mij))) +
             tc[k];
      m = fmaxf(m, x[k]);
    }
    float s2 = 0.f;
#pragma unroll
    for (int k = 0; k < 9; ++k) s2 += __expf(x[k] - m);
    float nxt = m + __logf(s2) + ev[s];
    bool apply = valid && (mv[s] != 0) && !(c == 0 && s == 0);
    mij = apply ? nxt : mij;
  }

  if (valid) chunkM[(size_t)(b * NCHUNK + c) * 81 + i * 9 + j] = mij;
}

// ---------------------------------------------------------------------------
// Kernel 3: per batch: fold alpha0 through 16 chunk matrices -> denom;
// numerator; atomicAdd(out, denom - num). One wave per batch.
// ---------------------------------------------------------------------------
__global__ __launch_bounds__(64) void final_kernel(
    const float* __restrict__ em, const int* __restrict__ mask,
    const int* __restrict__ labels, const float* __restrict__ st,
    const float* __restrict__ et, const float* __restrict__ trans,
    const float* __restrict__ chunkM, float* __restrict__ out) {
  const int b = blockIdx.x;
  const int lane = threadIdx.x;

  float v = 0.f;
  if (lane < LL) v = st[lane] + em[((size_t)b * SS) * LL + lane];

  for (int c = 0; c < NCHUNK; ++c) {
    const float* M = chunkM + ((size_t)(b * NCHUNK + c)) * 81;
    float vk[9];
#pragma unroll
    for (int k = 0; k < 9; ++k) vk[k] = __shfl(v, k);
    if (lane < LL) {
      float x[9];
      float m = -3e38f;
#pragma unroll
      for (int k = 0; k < 9; ++k) {
        x[k] = vk[k] + M[k * 9 + lane];
        m = fmaxf(m, x[k]);
      }
      float s = 0.f;
#pragma unroll
      for (int k = 0; k < 9; ++k) s += __expf(x[k] - m);
      v = m + __logf(s);
    }
  }

  float vj[9];
#pragma unroll
  for (int k = 0; k < 9; ++k) vj[k] = __shfl(v, k) + et[k];
  float m = -3e38f;
#pragma unroll
  for (int k = 0; k < 9; ++k) m = fmaxf(m, vj[k]);
  float s = 0.f;
#pragma unroll
  for (int k = 0; k < 9; ++k) s += __expf(vj[k] - m);
  float denom = m + __logf(s);

  const int* lab = labels + b * SS;
  const int* mk = mask + b * SS;
  float part = 0.f;
  int cnt = 0;
  for (int tt = lane; tt < SS; tt += 64) {
    int mvv = mk[tt];
    cnt += mvv;
    if (tt >= 1 && mvv) {
      int lp = lab[tt - 1], lc = lab[tt];
      part += trans[lp * LL + lc] + em[((size_t)(b * SS + tt)) * LL + lc];
    }
  }
#pragma unroll
  for (int off = 32; off; off >>= 1) {
    part += __shfl_xor(part, off);
    cnt += __shfl_xor(cnt, off);
  }
  if (lane == 0) {
    int last = cnt - 1;
    float num = st[lab[0]] + em[((size_t)b * SS) * LL + lab[0]] + part + et[lab[last]];
    atomicAdd(out, denom - num);
  }
}

extern "C" void kernel_launch(void* const* d_in, const int* in_sizes, int n_in,
                              void* d_out, int out_size, void* d_ws, size_t ws_size,
                              hipStream_t stream) {
  const float* hs     = (const float*)d_in[0];
  const int*   mask   = (const int*)d_in[1];
  const int*   labels = (const int*)d_in[2];
  const float* W      = (const float*)d_in[3];
  const float* bias   = (const float*)d_in[4];
  const float* st     = (const float*)d_in[5];
  const float* et     = (const float*)d_in[6];
  const float* trans  = (const float*)d_in[7];

  float* em     = (float*)d_ws;                      // 64*512*9 f32
  float* chunkM = em + (size_t)BB * SS * LL;         // 64*16*81 f32
  float* out    = (float*)d_out;

  emis_mfma<<<NTILE / 4, 256, 0, stream>>>(hs, W, bias, em, out);
  chunk_kernel<<<K2_BLOCKS, 256, 0, stream>>>(em, mask, trans, chunkM);
  final_kernel<<<BB, 64, 0, stream>>>(em, mask, labels, st, et, trans, chunkM, out);
}

// Round 3
// 52.231 us; speedup vs baseline: 1.4248x; 1.0468x over previous
//
#include <hip/hip_runtime.h>

typedef __attribute__((ext_vector_type(8))) short short8v;
typedef __attribute__((ext_vector_type(4))) float float4v;

constexpr int BB = 64, SS = 512, HH = 768, LL = 9, NCHUNK = 16, CHUNK = 32;
constexpr int KSTEPS = HH / 32;  // 24

// ---------------------------------------------------------------------------
// Kernel 0: pack W^T into per-(kstep,lane) bf16 MFMA A-fragments.
// A[row=label][k], row = lane&15 (labels 9..15 zero), k = (lane>>4)*8 + e.
// Also zero out[0] and numAcc[0..63].
// ---------------------------------------------------------------------------
__global__ __launch_bounds__(64) void packW_kernel(
    const float* __restrict__ W, unsigned short* __restrict__ packedW,
    float* __restrict__ numAcc, float* __restrict__ out) {
  const int s = blockIdx.x;      // kstep 0..23
  const int l = threadIdx.x;     // lane 0..63
  const int label = l & 15;
  const int kb = l >> 4;
  union { unsigned short u[8]; short8v v; } P;
#pragma unroll
  for (int e = 0; e < 8; ++e) {
    int k = s * 32 + kb * 8 + e;
    float f = (label < LL) ? W[(size_t)k * LL + label] : 0.f;
    P.u[e] = (unsigned short)(__float_as_uint(f) >> 16);
  }
  *reinterpret_cast<short8v*>(packedW + ((size_t)(s * 64 + l)) * 8) = P.v;
  if (s == 0) {
    if (l < BB) numAcc[l] = 0.f;
    if (l == 0) out[0] = 0.f;
  }
}

// ---------------------------------------------------------------------------
// Kernel 1 (fused): per (b,c) block of 128 threads (2 waves):
//   1. MFMA emissions for its 32 positions (wave w -> 16-pos tile w),
//      A = packedW frags (registers, L2), B = hs tile (bf16 via v_perm).
//      D[row=label][col=pos]; +bias -> LDS emLDS[32][9].
//   2. Barrier-free 9x9 log-semiring chunk product (81 slots across 2 waves,
//      rows of 9 lanes within one wave, ds_bpermute row broadcast).
//      c==0: row 0 initialized to start_trans + em[t=0] (alpha0 vector).
//   3. Interior numerator terms for its positions -> atomicAdd(numAcc[b]).
// ---------------------------------------------------------------------------
__global__ __launch_bounds__(128) void fused_kernel(
    const float* __restrict__ hs, const int* __restrict__ mask,
    const int* __restrict__ labels, const unsigned short* __restrict__ packedW,
    const float* __restrict__ bias, const float* __restrict__ st,
    const float* __restrict__ trans, float* __restrict__ chunkM,
    float* __restrict__ numAcc) {
  const int bc = blockIdx.x;
  const int b = bc >> 4;
  const int c = bc & 15;
  const int tid = threadIdx.x;
  const int wave = tid >> 6;
  const int lane = tid & 63;
  const int rc = lane & 15;
  const int kb = lane >> 4;

  __shared__ float emLDS[CHUNK * LL];

  // ---- phase 1: emissions tile via MFMA ----
  const int posg = b * SS + c * CHUNK + wave * 16;  // global row of hs
  const float* aptr = hs + (size_t)(posg + rc) * HH + kb * 8;
  const short8v* pw = reinterpret_cast<const short8v*>(packedW);

  float4v acc = {0.f, 0.f, 0.f, 0.f};
#pragma unroll 6
  for (int s = 0; s < KSTEPS; ++s) {
    float4 a0 = *reinterpret_cast<const float4*>(aptr + s * 32);
    float4 a1 = *reinterpret_cast<const float4*>(aptr + s * 32 + 4);
    union { unsigned u[4]; short8v v; } Bf;
    Bf.u[0] = __builtin_amdgcn_perm(__float_as_uint(a0.y), __float_as_uint(a0.x), 0x07060302u);
    Bf.u[1] = __builtin_amdgcn_perm(__float_as_uint(a0.w), __float_as_uint(a0.z), 0x07060302u);
    Bf.u[2] = __builtin_amdgcn_perm(__float_as_uint(a1.y), __float_as_uint(a1.x), 0x07060302u);
    Bf.u[3] = __builtin_amdgcn_perm(__float_as_uint(a1.w), __float_as_uint(a1.z), 0x07060302u);
    short8v Af = pw[s * 64 + lane];
    acc = __builtin_amdgcn_mfma_f32_16x16x32_bf16(Af, Bf.v, acc, 0, 0, 0);
  }
  // D: row(label) = kb*4+r, col(pos) = rc
  if (kb < 3) {
#pragma unroll
    for (int r = 0; r < 4; ++r) {
      int label = kb * 4 + r;
      if (label < LL)
        emLDS[(wave * 16 + rc) * LL + label] = acc[r] + bias[label];
    }
  }
  __syncthreads();

  // ---- phase 2: chunk log-semiring product ----
  bool valid;
  int q;
  if (wave == 0) { valid = lane < 63; q = valid ? lane : 0; }
  else           { valid = lane < 18; q = valid ? 63 + lane : 0; }
  const int i = q / 9, j = q % 9;
  const int rowbase = lane - j;  // lane of (row i, k=0) within this wave

  int addr[9];
#pragma unroll
  for (int k = 0; k < 9; ++k) addr[k] = (rowbase + k) * 4;

  float tc[9];
#pragma unroll
  for (int k = 0; k < 9; ++k) tc[k] = trans[k * LL + j];

  float ev[CHUNK];
#pragma unroll
  for (int s = 0; s < CHUNK; ++s) ev[s] = emLDS[s * LL + j];

  const int* mkp = mask + b * SS + c * CHUNK;
  int mv[CHUNK];
#pragma unroll
  for (int s = 0; s < CHUNK; ++s) mv[s] = mkp[s];

  float mij;
  if (c == 0 && i == 0) mij = st[j] + emLDS[j];        // alpha0[j]
  else                  mij = (i == j) ? 0.f : -1e30f; // identity row

#pragma unroll
  for (int s = 0; s < CHUNK; ++s) {
    float x[9];
    float m = -3e38f;
#pragma unroll
    for (int k = 0; k < 9; ++k) {
      x[k] = __int_as_float(
                 __builtin_amdgcn_ds_bpermute(addr[k], __float_as_int(mij))) +
             tc[k];
      m = fmaxf(m, x[k]);
    }
    float s2 = 0.f;
#pragma unroll
    for (int k = 0; k < 9; ++k) s2 += __expf(x[k] - m);
    float nxt = m + __logf(s2) + ev[s];
    bool apply = valid && (mv[s] != 0) && !(c == 0 && s == 0);
    mij = apply ? nxt : mij;
  }
  if (valid) chunkM[(size_t)bc * 81 + q] = mij;

  // ---- phase 3: numerator interior terms ----
  float val = 0.f;
  if (wave == 0 && lane < CHUNK) {
    const int* lab = labels + b * SS;
    int tg = c * CHUNK + lane;
    if (tg >= 1 && mkp[lane] != 0) {
      int lp = lab[tg - 1], lc = lab[tg];
      val = trans[lp * LL + lc] + emLDS[lane * LL + lc];
    }
    if (c == 0 && lane == 0) {
      int l0 = lab[0];
      val += st[l0] + emLDS[l0];
    }
  }
  if (wave == 0) {
#pragma unroll
    for (int off = 16; off; off >>= 1) val += __shfl_xor(val, off);
    if (lane == 0) atomicAdd(numAcc + b, val);
  }
}

// ---------------------------------------------------------------------------
// Kernel 2: per batch: v = chunkM[b][0].row0 (alpha after chunk 0), fold 15
// matrices, denom = lse(v + end_trans); out += denom - end_term - numAcc[b].
// ---------------------------------------------------------------------------
__global__ __launch_bounds__(64) void final_kernel(
    const int* __restrict__ mask, const int* __restrict__ labels,
    const float* __restrict__ et, const float* __restrict__ chunkM,
    const float* __restrict__ numAcc, float* __restrict__ out) {
  const int b = blockIdx.x;
  const int lane = threadIdx.x;
  const float* Mb = chunkM + (size_t)b * NCHUNK * 81;

  float v = (lane < LL) ? Mb[lane] : 0.f;  // row 0 of chunk 0
  for (int c = 1; c < NCHUNK; ++c) {
    const float* M = Mb + c * 81;
    float vk[9];
#pragma unroll
    for (int k = 0; k < 9; ++k) vk[k] = __shfl(v, k);
    if (lane < LL) {
      float x[9];
      float m = -3e38f;
#pragma unroll
      for (int k = 0; k < 9; ++k) {
        x[k] = vk[k] + M[k * 9 + lane];
        m = fmaxf(m, x[k]);
      }
      float s = 0.f;
#pragma unroll
      for (int k = 0; k < 9; ++k) s += __expf(x[k] - m);
      v = m + __logf(s);
    }
  }

  float vj[9];
#pragma unroll
  for (int k = 0; k < 9; ++k) vj[k] = __shfl(v, k) + et[k];
  float m = -3e38f;
#pragma unroll
  for (int k = 0; k < 9; ++k) m = fmaxf(m, vj[k]);
  float s = 0.f;
#pragma unroll
  for (int k = 0; k < 9; ++k) s += __expf(vj[k] - m);
  float denom = m + __logf(s);

  const int* mk = mask + b * SS;
  int cnt = 0;
  for (int tt = lane; tt < SS; tt += 64) cnt += mk[tt];
#pragma unroll
  for (int off = 32; off; off >>= 1) cnt += __shfl_xor(cnt, off);

  if (lane == 0) {
    int last = cnt - 1;
    float etterm = et[labels[b * SS + last]];
    atomicAdd(out, denom - etterm - numAcc[b]);
  }
}

extern "C" void kernel_launch(void* const* d_in, const int* in_sizes, int n_in,
                              void* d_out, int out_size, void* d_ws, size_t ws_size,
                              hipStream_t stream) {
  const float* hs     = (const float*)d_in[0];
  const int*   mask   = (const int*)d_in[1];
  const int*   labels = (const int*)d_in[2];
  const float* W      = (const float*)d_in[3];
  const float* bias   = (const float*)d_in[4];
  const float* st     = (const float*)d_in[5];
  const float* et     = (const float*)d_in[6];
  const float* trans  = (const float*)d_in[7];

  float* chunkM = (float*)d_ws;                                  // 64*16*81 f32
  unsigned short* packedW =
      (unsigned short*)(chunkM + (size_t)BB * NCHUNK * 81);      // 24*64*8 bf16
  float* numAcc = (float*)(packedW + (size_t)KSTEPS * 64 * 8);   // 64 f32
  float* out    = (float*)d_out;

  packW_kernel<<<KSTEPS, 64, 0, stream>>>(W, packedW, numAcc, out);
  fused_kernel<<<BB * NCHUNK, 128, 0, stream>>>(hs, mask, labels, packedW,
                                                bias, st, trans, chunkM, numAcc);
  final_kernel<<<BB, 64, 0, stream>>>(mask, labels, et, chunkM, numAcc, out);
}